// Round 7
// baseline (102.222 us; speedup 1.0000x reference)
//
#include <hip/hip_runtime.h>

#define NB 8
#define NA 120000
#define NK 80
#define NM 32

#define ALPHA_F 0.25f
#define EPS_F 1e-4f

#define BLK 256
#define BPB ((NA + BLK - 1) / BLK)          // 469 blocks per batch item (last has 192 rows)

// ws: float4 part[NB*BPB] (cls, reg, pos, pad) — plain stores, every slot written each launch

__device__ __forceinline__ float clampc(float x) {
    return fminf(fmaxf(x, EPS_F), 1.0f - EPS_F);
}
__device__ __forceinline__ float negl(float c) {
    // t == 0: (1-alpha) * c^2 * (-log(1-c))
    return (1.0f - ALPHA_F) * c * c * (-__logf(1.0f - c));
}
__device__ __forceinline__ float posl(float c) {
    // t == 1: alpha * (1-c)^2 * (-log(c))
    const float omc = 1.0f - c;
    return ALPHA_F * omc * omc * (-__logf(c));
}
__device__ __forceinline__ float negl4(float4 v) {
    return negl(clampc(v.x)) + negl(clampc(v.y)) + negl(clampc(v.z)) + negl(clampc(v.w));
}

__global__ __launch_bounds__(BLK) void fused_kernel(
    const float* __restrict__ anchors,      // [NA,4]
    const float* __restrict__ regressions,  // [NB,NA,4]
    const float* __restrict__ annotations,  // [NB,NM,5]
    const float* __restrict__ cls,          // [NB,NA,NK]
    float* __restrict__ part)               // [NB*BPB] float4
{
    const int b = blockIdx.x / BPB;
    const int blk = blockIdx.x % BPB;
    const int a0 = blk * BLK;
    const int a = a0 + threadIdx.x;

    __shared__ float ann[NM * 5];
    __shared__ float barea[NM];
    __shared__ int s_ign[BLK];              // block-local ignore-row list
    __shared__ int s_nign;
    if (threadIdx.x == 0) s_nign = 0;
    if (threadIdx.x < NM * 5) ann[threadIdx.x] = annotations[b * NM * 5 + threadIdx.x];
    __syncthreads();
    if (threadIdx.x < NM) {
        const float* r = &ann[threadIdx.x * 5];
        barea[threadIdx.x] = (r[2] - r[0]) * (r[3] - r[1]);
    }
    __syncthreads();

    const float4* __restrict__ p = (const float4*)(cls + ((size_t)b * NA + a0) * NK);
    const float4* __restrict__ q = p + threadIdx.x;
    const int n_rows = (a0 + BLK <= NA) ? BLK : (NA - a0);
    const bool full = (n_rows == BLK);

    // ---- prefetch batches 0 and 1 BEFORE phase 1: phase-1 VALU hides load latency ----
    float4 A[5], B[5];
    if (full) {
        #pragma unroll
        for (int u = 0; u < 5; ++u) A[u] = q[u * BLK];
        #pragma unroll
        for (int u = 0; u < 5; ++u) B[u] = q[(5 + u) * BLK];
    }

    float reg_local = 0.0f;
    float pos_local = 0.0f;
    float cls_local = 0.0f;

    // ---- phase 1: anchor assignment (one anchor per thread) ----
    if (a < NA) {
        const float4 av = ((const float4*)anchors)[a];
        const float aw = av.z - av.x;
        const float ah = av.w - av.y;
        const float aarea = aw * ah;

        // division-free argmax over (inter, ua); strict > keeps first occurrence
        float bi = -1.0f, bu = 1.0f;
        int bm = 0;
        #pragma unroll
        for (int m = 0; m < NM; ++m) {
            const float bx1 = ann[m * 5 + 0];
            const float by1 = ann[m * 5 + 1];
            const float bx2 = ann[m * 5 + 2];
            const float by2 = ann[m * 5 + 3];
            const float lbl = ann[m * 5 + 4];
            const float iw = fmaxf(fminf(av.z, bx2) - fmaxf(av.x, bx1), 0.0f);
            const float ih = fmaxf(fminf(av.w, by2) - fmaxf(av.y, by1), 0.0f);
            float inter = iw * ih;
            float ua = fmaxf(aarea + barea[m] - inter, 1e-8f);
            if (lbl == -1.0f) { inter = -1.0f; ua = 1.0f; }
            if (m == 0 || inter * bu > bi * ua) { bi = inter; bu = ua; bm = m; }
        }

        if (bi >= 0.5f * bu) {
            // POSITIVE: smooth-L1 + single-element class correction (rare, exec-masked)
            const int st = (int)ann[bm * 5 + 4];
            const float bx1 = ann[bm * 5 + 0];
            const float by1 = ann[bm * 5 + 1];
            const float bx2 = ann[bm * 5 + 2];
            const float by2 = ann[bm * 5 + 3];
            const float gw0 = bx2 - bx1;
            const float gh0 = by2 - by1;
            const float gcx = bx1 + 0.5f * gw0;
            const float gcy = by1 + 0.5f * gh0;
            const float gw = fmaxf(gw0, 1.0f);
            const float gh = fmaxf(gh0, 1.0f);
            const float acx = av.x + 0.5f * aw;
            const float acy = av.y + 0.5f * ah;
            const float rt0 = ((gcx - acx) / aw) / 0.1f;
            const float rt1 = ((gcy - acy) / ah) / 0.1f;
            const float rt2 = logf(gw / aw) / 0.2f;
            const float rt3 = logf(gh / ah) / 0.2f;
            const float4 rg = ((const float4*)regressions)[b * NA + a];
            float s = 0.0f, d;
            d = fabsf(rt0 - rg.x); s += (d <= 1.0f / 9.0f) ? 4.5f * d * d : d - 0.5f / 9.0f;
            d = fabsf(rt1 - rg.y); s += (d <= 1.0f / 9.0f) ? 4.5f * d * d : d - 0.5f / 9.0f;
            d = fabsf(rt2 - rg.z); s += (d <= 1.0f / 9.0f) ? 4.5f * d * d : d - 0.5f / 9.0f;
            d = fabsf(rt3 - rg.w); s += (d <= 1.0f / 9.0f) ? 4.5f * d * d : d - 0.5f / 9.0f;
            reg_local = s;
            pos_local = 1.0f;
            const float c = clampc(cls[((size_t)b * NA + a) * NK + st]);
            cls_local = posl(c) - negl(c);
        } else if (bi >= 0.4f * bu) {
            // IGNORE: record row for phase-3 subtraction (LDS atomic, few per block)
            const int k = atomicAdd(&s_nign, 1);
            s_ign[k] = threadIdx.x;
        }
        // else NEGATIVE: pure stream counts it correctly
    }
    __syncthreads();

    // ---- phase 2: software-pipelined stream (compute batch k while k+1 in flight) ----
    if (full) {
        float s = 0.0f;
        #pragma unroll
        for (int u = 0; u < 5; ++u) s += negl4(A[u]);       // compute b0 (b1 in flight)
        #pragma unroll
        for (int u = 0; u < 5; ++u) A[u] = q[(10 + u) * BLK]; // issue b2
        #pragma unroll
        for (int u = 0; u < 5; ++u) s += negl4(B[u]);       // compute b1 (b2 in flight)
        #pragma unroll
        for (int u = 0; u < 5; ++u) B[u] = q[(15 + u) * BLK]; // issue b3
        #pragma unroll
        for (int u = 0; u < 5; ++u) s += negl4(A[u]);       // compute b2 (b3 in flight)
        #pragma unroll
        for (int u = 0; u < 5; ++u) s += negl4(B[u]);       // compute b3
        cls_local += s;
    } else {
        const int n4 = n_rows * 20;
        for (int idx = threadIdx.x; idx < n4; idx += BLK)
            cls_local += negl4(p[idx]);
    }

    // ---- phase 3: subtract ignore rows (cache-resident re-read) ----
    const int nign = s_nign;
    if (nign > 0) {
        const int total = nign * 20;
        for (int i = threadIdx.x; i < total; i += BLK) {
            const int e = i / 20;
            const int f = i - e * 20;
            const int r = s_ign[e];
            cls_local -= negl4(p[r * 20 + f]);
        }
    }

    // ---- block reduction, plain store ----
    #pragma unroll
    for (int o = 32; o > 0; o >>= 1) {
        cls_local += __shfl_down(cls_local, o, 64);
        reg_local += __shfl_down(reg_local, o, 64);
        pos_local += __shfl_down(pos_local, o, 64);
    }
    __shared__ float wc[BLK / 64], wr[BLK / 64], wp[BLK / 64];
    const int lane = threadIdx.x & 63;
    const int wid = threadIdx.x >> 6;
    if (lane == 0) { wc[wid] = cls_local; wr[wid] = reg_local; wp[wid] = pos_local; }
    __syncthreads();
    if (threadIdx.x == 0) {
        float csum = 0.0f, rsum = 0.0f, psum = 0.0f;
        #pragma unroll
        for (int i = 0; i < BLK / 64; ++i) { csum += wc[i]; rsum += wr[i]; psum += wp[i]; }
        float4 o4;
        o4.x = csum; o4.y = rsum; o4.z = psum; o4.w = 0.0f;
        ((float4*)part)[blockIdx.x] = o4;
    }
}

// 512 threads = 8 waves, wave w reduces batch item w; shuffle-only, one barrier.
__global__ __launch_bounds__(512) void finalize_kernel(
    const float* __restrict__ part,
    float* __restrict__ out)
{
    __shared__ float redC[NB], redR[NB], redP[NB];
    const int w = threadIdx.x >> 6;        // batch item
    const int lane = threadIdx.x & 63;

    float c = 0.0f, r = 0.0f, p = 0.0f;
    for (int i = lane; i < BPB; i += 64) {
        const float4 q = ((const float4*)part)[w * BPB + i];
        c += q.x; r += q.y; p += q.z;
    }
    #pragma unroll
    for (int o = 32; o > 0; o >>= 1) {
        c += __shfl_down(c, o, 64);
        r += __shfl_down(r, o, 64);
        p += __shfl_down(p, o, 64);
    }
    if (lane == 0) { redC[w] = c; redR[w] = r; redP[w] = p; }
    __syncthreads();
    if (threadIdx.x == 0) {
        float cs = 0.0f, rs = 0.0f;
        #pragma unroll
        for (int b = 0; b < NB; ++b) {
            const float P = redP[b];
            cs += redC[b] / fmaxf(P, 1.0f);
            rs += (P > 0.0f) ? redR[b] / fmaxf(P * 4.0f, 1.0f) : 0.0f;
        }
        out[0] = cs / (float)NB;
        out[1] = rs / (float)NB;
    }
}

extern "C" void kernel_launch(void* const* d_in, const int* in_sizes, int n_in,
                              void* d_out, int out_size, void* d_ws, size_t ws_size,
                              hipStream_t stream) {
    const float* cls = (const float*)d_in[0];   // [NB,NA,NK]
    const float* reg = (const float*)d_in[1];   // [NB,NA,4]
    const float* anc = (const float*)d_in[2];   // [1,NA,4]
    const float* ann = (const float*)d_in[3];   // [NB,NM,5]

    float* part = (float*)d_ws;
    float* out = (float*)d_out;

    fused_kernel<<<NB * BPB, BLK, 0, stream>>>(anc, reg, ann, cls, part);
    finalize_kernel<<<1, 512, 0, stream>>>(part, out);
}

// Round 8
// 83.708 us; speedup vs baseline: 1.2212x; 1.2212x over previous
//
#include <hip/hip_runtime.h>

#define NB 8
#define NA 120000
#define NK 80
#define NM 32

#define ALPHA_F 0.25f
#define EPS_F 1e-4f

#define TPB (NA / 64)                       // 1875 wave-tiles per batch item (exact: 64*1875)
#define BLKW 4                              // waves per block
#define BPBW ((TPB + BLKW - 1) / BLKW)      // 469 blocks per batch item

// ws: float4 part[NB][TPB] (cls, reg, pos, pad) — per-WAVE partials, plain stores (240 KB)

__device__ __forceinline__ float clampc(float x) {
    return fminf(fmaxf(x, EPS_F), 1.0f - EPS_F);
}
__device__ __forceinline__ float negl(float c) {
    // t == 0: (1-alpha) * c^2 * (-log(1-c))
    return (1.0f - ALPHA_F) * c * c * (-__logf(1.0f - c));
}
__device__ __forceinline__ float posl(float c) {
    // t == 1: alpha * (1-c)^2 * (-log(c))
    const float omc = 1.0f - c;
    return ALPHA_F * omc * omc * (-__logf(c));
}
__device__ __forceinline__ float negl4(float4 v) {
    return negl(clampc(v.x)) + negl(clampc(v.y)) + negl(clampc(v.z)) + negl(clampc(v.w));
}

__global__ __launch_bounds__(256) void fused_kernel(
    const float* __restrict__ anchors,      // [NA,4]
    const float* __restrict__ regressions,  // [NB,NA,4]
    const float* __restrict__ annotations,  // [NB,NM,5]
    const float* __restrict__ cls,          // [NB,NA,NK]
    float* __restrict__ part)               // [NB*TPB] float4
{
    const int b = blockIdx.x / BPBW;
    const int blk = blockIdx.x % BPBW;
    const int wid = threadIdx.x >> 6;
    const int lane = threadIdx.x & 63;
    const int tile = blk * BLKW + wid;      // this wave's 64-anchor tile

    __shared__ float ann[NM * 5];
    __shared__ float barea[NM];
    if (threadIdx.x < NM * 5) ann[threadIdx.x] = annotations[b * NM * 5 + threadIdx.x];
    __syncthreads();
    if (threadIdx.x < NM) {
        const float* r = &ann[threadIdx.x * 5];
        barea[threadIdx.x] = (r[2] - r[0]) * (r[3] - r[1]);
    }
    __syncthreads();                        // last barrier in the kernel: waves free-run after this

    if (tile >= TPB) return;                // at most 1 idle wave per batch item

    const int a = tile * 64 + lane;         // anchor id, always < NA

    float reg_local = 0.0f;
    float pos_local = 0.0f;
    float cls_local = 0.0f;
    float maskf = 1.0f;                     // 0 for ignore rows, 1 otherwise

    // ---- phase 1 (per-lane, no sync): IoU argmax + status + positive corrections ----
    {
        const float4 av = ((const float4*)anchors)[a];
        const float aw = av.z - av.x;
        const float ah = av.w - av.y;
        const float aarea = aw * ah;

        // division-free argmax over (inter, ua); strict > keeps first occurrence
        float bi = -1.0f, bu = 1.0f;
        int bm = 0;
        #pragma unroll
        for (int m = 0; m < NM; ++m) {
            const float bx1 = ann[m * 5 + 0];
            const float by1 = ann[m * 5 + 1];
            const float bx2 = ann[m * 5 + 2];
            const float by2 = ann[m * 5 + 3];
            const float lbl = ann[m * 5 + 4];
            const float iw = fmaxf(fminf(av.z, bx2) - fmaxf(av.x, bx1), 0.0f);
            const float ih = fmaxf(fminf(av.w, by2) - fmaxf(av.y, by1), 0.0f);
            float inter = iw * ih;
            float ua = fmaxf(aarea + barea[m] - inter, 1e-8f);
            if (lbl == -1.0f) { inter = -1.0f; ua = 1.0f; }
            if (m == 0 || inter * bu > bi * ua) { bi = inter; bu = ua; bm = m; }
        }

        if (bi >= 0.5f * bu) {
            // POSITIVE: smooth-L1 + single-element class correction (rare, exec-masked)
            const int st = (int)ann[bm * 5 + 4];
            const float bx1 = ann[bm * 5 + 0];
            const float by1 = ann[bm * 5 + 1];
            const float bx2 = ann[bm * 5 + 2];
            const float by2 = ann[bm * 5 + 3];
            const float gw0 = bx2 - bx1;
            const float gh0 = by2 - by1;
            const float gcx = bx1 + 0.5f * gw0;
            const float gcy = by1 + 0.5f * gh0;
            const float gw = fmaxf(gw0, 1.0f);
            const float gh = fmaxf(gh0, 1.0f);
            const float acx = av.x + 0.5f * aw;
            const float acy = av.y + 0.5f * ah;
            const float rt0 = ((gcx - acx) / aw) / 0.1f;
            const float rt1 = ((gcy - acy) / ah) / 0.1f;
            const float rt2 = logf(gw / aw) / 0.2f;
            const float rt3 = logf(gh / ah) / 0.2f;
            const float4 rg = ((const float4*)regressions)[b * NA + a];
            float s = 0.0f, d;
            d = fabsf(rt0 - rg.x); s += (d <= 1.0f / 9.0f) ? 4.5f * d * d : d - 0.5f / 9.0f;
            d = fabsf(rt1 - rg.y); s += (d <= 1.0f / 9.0f) ? 4.5f * d * d : d - 0.5f / 9.0f;
            d = fabsf(rt2 - rg.z); s += (d <= 1.0f / 9.0f) ? 4.5f * d * d : d - 0.5f / 9.0f;
            d = fabsf(rt3 - rg.w); s += (d <= 1.0f / 9.0f) ? 4.5f * d * d : d - 0.5f / 9.0f;
            reg_local = s;
            pos_local = 1.0f;
            const float c = clampc(cls[((size_t)b * NA + a) * NK + st]);
            cls_local = posl(c) - negl(c);
        } else if (bi >= 0.4f * bu) {
            maskf = 0.0f;                   // IGNORE: row contributes nothing
        }
    }

    // ---- phase 2 (per-wave, no sync): stream this wave's 64x80 tile ----
    // 1280 float4 = 4 outer x 5-deep batches; mask via ds_bpermute from owning lane.
    const float4* __restrict__ p = (const float4*)(cls + ((size_t)b * NA + (size_t)tile * 64) * NK);
    float sum = 0.0f;
    #pragma unroll
    for (int o = 0; o < 4; ++o) {
        float4 v[5];
        #pragma unroll
        for (int u = 0; u < 5; ++u)
            v[u] = p[(o * 5 + u) * 64 + lane];
        #pragma unroll
        for (int u = 0; u < 5; ++u) {
            const int flat = (o * 5 + u) * 64 + lane;
            const int row = flat / 20;      // const-div -> magic mul; row in [0,64)
            const float m = __shfl(maskf, row, 64);
            sum += m * negl4(v[u]);
        }
    }
    cls_local += sum;

    // ---- wave reduction, lane-0 store (no block reduce, no barrier) ----
    #pragma unroll
    for (int o = 32; o > 0; o >>= 1) {
        cls_local += __shfl_down(cls_local, o, 64);
        reg_local += __shfl_down(reg_local, o, 64);
        pos_local += __shfl_down(pos_local, o, 64);
    }
    if (lane == 0) {
        float4 o4;
        o4.x = cls_local; o4.y = reg_local; o4.z = pos_local; o4.w = 0.0f;
        ((float4*)part)[b * TPB + tile] = o4;
    }
}

// 512 threads = 8 waves, wave w reduces batch item w; shuffle-only, one barrier.
__global__ __launch_bounds__(512) void finalize_kernel(
    const float* __restrict__ part,
    float* __restrict__ out)
{
    __shared__ float redC[NB], redR[NB], redP[NB];
    const int w = threadIdx.x >> 6;        // batch item
    const int lane = threadIdx.x & 63;

    float c = 0.0f, r = 0.0f, p = 0.0f;
    for (int i = lane; i < TPB; i += 64) {
        const float4 q = ((const float4*)part)[w * TPB + i];
        c += q.x; r += q.y; p += q.z;
    }
    #pragma unroll
    for (int o = 32; o > 0; o >>= 1) {
        c += __shfl_down(c, o, 64);
        r += __shfl_down(r, o, 64);
        p += __shfl_down(p, o, 64);
    }
    if (lane == 0) { redC[w] = c; redR[w] = r; redP[w] = p; }
    __syncthreads();
    if (threadIdx.x == 0) {
        float cs = 0.0f, rs = 0.0f;
        #pragma unroll
        for (int b = 0; b < NB; ++b) {
            const float P = redP[b];
            cs += redC[b] / fmaxf(P, 1.0f);
            rs += (P > 0.0f) ? redR[b] / fmaxf(P * 4.0f, 1.0f) : 0.0f;
        }
        out[0] = cs / (float)NB;
        out[1] = rs / (float)NB;
    }
}

extern "C" void kernel_launch(void* const* d_in, const int* in_sizes, int n_in,
                              void* d_out, int out_size, void* d_ws, size_t ws_size,
                              hipStream_t stream) {
    const float* cls = (const float*)d_in[0];   // [NB,NA,NK]
    const float* reg = (const float*)d_in[1];   // [NB,NA,4]
    const float* anc = (const float*)d_in[2];   // [1,NA,4]
    const float* ann = (const float*)d_in[3];   // [NB,NM,5]

    float* part = (float*)d_ws;
    float* out = (float*)d_out;

    fused_kernel<<<NB * BPBW, 256, 0, stream>>>(anc, reg, ann, cls, part);
    finalize_kernel<<<1, 512, 0, stream>>>(part, out);
}

// Round 9
// 76.656 us; speedup vs baseline: 1.3335x; 1.0920x over previous
//
#include <hip/hip_runtime.h>

#define NB 8
#define NA 120000
#define NK 80
#define NM 32

#define ALPHA_F 0.25f
#define EPS_F 1e-4f

#define TPB (NA / 64)                       // 1875 wave-tiles per batch item (exact: 64*1875)
#define BLKW 4                              // waves per block
#define BPBW ((TPB + BLKW - 1) / BLKW)      // 469 blocks per batch item

// ws: float4 part[NB*BPBW] (cls, reg, pos, pad) — per-BLOCK partials, plain stores (60 KB)

typedef float f32x4 __attribute__((ext_vector_type(4)));

__device__ __forceinline__ f32x4 ntload4(const f32x4* p) {
    return __builtin_nontemporal_load(p);   // nt read: bypass L1/L2/MALL allocation
}

__device__ __forceinline__ float clampc(float x) {
    return fminf(fmaxf(x, EPS_F), 1.0f - EPS_F);
}
__device__ __forceinline__ float negl(float c) {
    // t == 0: (1-alpha) * c^2 * (-log(1-c))
    return (1.0f - ALPHA_F) * c * c * (-__logf(1.0f - c));
}
__device__ __forceinline__ float posl(float c) {
    // t == 1: alpha * (1-c)^2 * (-log(c))
    const float omc = 1.0f - c;
    return ALPHA_F * omc * omc * (-__logf(c));
}
__device__ __forceinline__ float negl4v(f32x4 v) {
    return negl(clampc(v.x)) + negl(clampc(v.y)) + negl(clampc(v.z)) + negl(clampc(v.w));
}

__global__ __launch_bounds__(256) void fused_kernel(
    const float* __restrict__ anchors,      // [NA,4]
    const float* __restrict__ regressions,  // [NB,NA,4]
    const float* __restrict__ annotations,  // [NB,NM,5]
    const float* __restrict__ cls,          // [NB,NA,NK]
    float* __restrict__ part)               // [NB*BPBW] float4
{
    const int b = blockIdx.x / BPBW;
    const int blk = blockIdx.x % BPBW;
    const int wid = threadIdx.x >> 6;
    const int lane = threadIdx.x & 63;
    const int tile = blk * BLKW + wid;      // this wave's 64-anchor tile

    __shared__ float ann[NM * 5];
    __shared__ float barea[NM];
    if (threadIdx.x < NM * 5) ann[threadIdx.x] = annotations[b * NM * 5 + threadIdx.x];
    __syncthreads();
    if (threadIdx.x < NM) {
        const float* r = &ann[threadIdx.x * 5];
        barea[threadIdx.x] = (r[2] - r[0]) * (r[3] - r[1]);
    }
    __syncthreads();

    float reg_local = 0.0f;
    float pos_local = 0.0f;
    float cls_local = 0.0f;

    if (tile < TPB) {                       // guarded (no early return: block reduce below)
        const int a = tile * 64 + lane;     // anchor id, always < NA
        float maskf = 1.0f;                 // 0 for ignore rows, 1 otherwise

        // ---- phase 1 (per-lane, no sync): IoU argmax + status + positive corrections ----
        {
            const float4 av = ((const float4*)anchors)[a];
            const float aw = av.z - av.x;
            const float ah = av.w - av.y;
            const float aarea = aw * ah;

            // division-free argmax over (inter, ua); strict > keeps first occurrence
            float bi = -1.0f, bu = 1.0f;
            int bm = 0;
            #pragma unroll
            for (int m = 0; m < NM; ++m) {
                const float bx1 = ann[m * 5 + 0];
                const float by1 = ann[m * 5 + 1];
                const float bx2 = ann[m * 5 + 2];
                const float by2 = ann[m * 5 + 3];
                const float lbl = ann[m * 5 + 4];
                const float iw = fmaxf(fminf(av.z, bx2) - fmaxf(av.x, bx1), 0.0f);
                const float ih = fmaxf(fminf(av.w, by2) - fmaxf(av.y, by1), 0.0f);
                float inter = iw * ih;
                float ua = fmaxf(aarea + barea[m] - inter, 1e-8f);
                if (lbl == -1.0f) { inter = -1.0f; ua = 1.0f; }
                if (m == 0 || inter * bu > bi * ua) { bi = inter; bu = ua; bm = m; }
            }

            if (bi >= 0.5f * bu) {
                // POSITIVE: smooth-L1 + single-element class correction (rare, exec-masked)
                const int st = (int)ann[bm * 5 + 4];
                const float bx1 = ann[bm * 5 + 0];
                const float by1 = ann[bm * 5 + 1];
                const float bx2 = ann[bm * 5 + 2];
                const float by2 = ann[bm * 5 + 3];
                const float gw0 = bx2 - bx1;
                const float gh0 = by2 - by1;
                const float gcx = bx1 + 0.5f * gw0;
                const float gcy = by1 + 0.5f * gh0;
                const float gw = fmaxf(gw0, 1.0f);
                const float gh = fmaxf(gh0, 1.0f);
                const float acx = av.x + 0.5f * aw;
                const float acy = av.y + 0.5f * ah;
                const float rt0 = ((gcx - acx) / aw) / 0.1f;
                const float rt1 = ((gcy - acy) / ah) / 0.1f;
                const float rt2 = logf(gw / aw) / 0.2f;
                const float rt3 = logf(gh / ah) / 0.2f;
                const float4 rg = ((const float4*)regressions)[b * NA + a];
                float s = 0.0f, d;
                d = fabsf(rt0 - rg.x); s += (d <= 1.0f / 9.0f) ? 4.5f * d * d : d - 0.5f / 9.0f;
                d = fabsf(rt1 - rg.y); s += (d <= 1.0f / 9.0f) ? 4.5f * d * d : d - 0.5f / 9.0f;
                d = fabsf(rt2 - rg.z); s += (d <= 1.0f / 9.0f) ? 4.5f * d * d : d - 0.5f / 9.0f;
                d = fabsf(rt3 - rg.w); s += (d <= 1.0f / 9.0f) ? 4.5f * d * d : d - 0.5f / 9.0f;
                reg_local = s;
                pos_local = 1.0f;
                const float c = clampc(cls[((size_t)b * NA + a) * NK + st]);
                cls_local = posl(c) - negl(c);
            } else if (bi >= 0.4f * bu) {
                maskf = 0.0f;               // IGNORE: row contributes nothing
            }
        }

        // ---- phase 2 (per-wave, no sync): nt-stream this wave's 64x80 tile ----
        const f32x4* __restrict__ p =
            (const f32x4*)(cls + ((size_t)b * NA + (size_t)tile * 64) * NK);
        float sum = 0.0f;
        #pragma unroll
        for (int o = 0; o < 4; ++o) {
            f32x4 v[5];
            #pragma unroll
            for (int u = 0; u < 5; ++u)
                v[u] = ntload4(p + (o * 5 + u) * 64 + lane);
            #pragma unroll
            for (int u = 0; u < 5; ++u) {
                const int flat = (o * 5 + u) * 64 + lane;
                const int row = flat / 20;  // const-div -> magic mul; row in [0,64)
                const float m = __shfl(maskf, row, 64);
                sum += m * negl4v(v[u]);
            }
        }
        cls_local += sum;
    }

    // ---- wave reduce, then cross-wave LDS reduce, one store per block ----
    #pragma unroll
    for (int o = 32; o > 0; o >>= 1) {
        cls_local += __shfl_down(cls_local, o, 64);
        reg_local += __shfl_down(reg_local, o, 64);
        pos_local += __shfl_down(pos_local, o, 64);
    }
    __shared__ float wc[BLKW], wr[BLKW], wp[BLKW];
    if (lane == 0) { wc[wid] = cls_local; wr[wid] = reg_local; wp[wid] = pos_local; }
    __syncthreads();
    if (threadIdx.x == 0) {
        float csum = 0.0f, rsum = 0.0f, psum = 0.0f;
        #pragma unroll
        for (int i = 0; i < BLKW; ++i) { csum += wc[i]; rsum += wr[i]; psum += wp[i]; }
        float4 o4;
        o4.x = csum; o4.y = rsum; o4.z = psum; o4.w = 0.0f;
        ((float4*)part)[blockIdx.x] = o4;
    }
}

// 512 threads = 8 waves, wave w reduces batch item w's 469 block-partials.
// 8-deep unrolled guarded loads -> all in flight at once, single latency.
__global__ __launch_bounds__(512) void finalize_kernel(
    const float* __restrict__ part,
    float* __restrict__ out)
{
    __shared__ float redC[NB], redR[NB], redP[NB];
    const int w = threadIdx.x >> 6;        // batch item
    const int lane = threadIdx.x & 63;

    float c = 0.0f, r = 0.0f, p = 0.0f;
    #pragma unroll
    for (int u = 0; u < 8; ++u) {          // 8*64 = 512 >= 469
        const int i = u * 64 + lane;
        if (i < BPBW) {
            const float4 q = ((const float4*)part)[w * BPBW + i];
            c += q.x; r += q.y; p += q.z;
        }
    }
    #pragma unroll
    for (int o = 32; o > 0; o >>= 1) {
        c += __shfl_down(c, o, 64);
        r += __shfl_down(r, o, 64);
        p += __shfl_down(p, o, 64);
    }
    if (lane == 0) { redC[w] = c; redR[w] = r; redP[w] = p; }
    __syncthreads();
    if (threadIdx.x == 0) {
        float cs = 0.0f, rs = 0.0f;
        #pragma unroll
        for (int b = 0; b < NB; ++b) {
            const float P = redP[b];
            cs += redC[b] / fmaxf(P, 1.0f);
            rs += (P > 0.0f) ? redR[b] / fmaxf(P * 4.0f, 1.0f) : 0.0f;
        }
        out[0] = cs / (float)NB;
        out[1] = rs / (float)NB;
    }
}

extern "C" void kernel_launch(void* const* d_in, const int* in_sizes, int n_in,
                              void* d_out, int out_size, void* d_ws, size_t ws_size,
                              hipStream_t stream) {
    const float* cls = (const float*)d_in[0];   // [NB,NA,NK]
    const float* reg = (const float*)d_in[1];   // [NB,NA,4]
    const float* anc = (const float*)d_in[2];   // [1,NA,4]
    const float* ann = (const float*)d_in[3];   // [NB,NM,5]

    float* part = (float*)d_ws;
    float* out = (float*)d_out;

    fused_kernel<<<NB * BPBW, 256, 0, stream>>>(anc, reg, ann, cls, part);
    finalize_kernel<<<1, 512, 0, stream>>>(part, out);
}